// Round 12
// baseline (323.310 us; speedup 1.0000x reference)
//
#include <hip/hip_runtime.h>
#include <cstdint>
#include <cstddef>

#define TAU_D 2.053748910631823
#define M_DIM 8192
#define N_DIM 4096
#define K_DIM 4096
#define NIT   32               // iterations; each covers 2 K-steps of BK=64

typedef float f32x4  __attribute__((ext_vector_type(4)));
typedef short bf16x8 __attribute__((ext_vector_type(8)));

typedef __attribute__((address_space(1))) void gvoid_t;
typedef __attribute__((address_space(3))) void lvoid_t;

__device__ __forceinline__ void gload_lds16(const void* g, void* l) {
    __builtin_amdgcn_global_load_lds((const gvoid_t*)g, (lvoid_t*)l, 16, 0, 0);
}

__device__ __forceinline__ unsigned int pack2bf(float lo, float hi) {
    unsigned int ul = __float_as_uint(lo);
    unsigned int uh = __float_as_uint(hi);
    ul = (ul + 0x7FFFu + ((ul >> 16) & 1u)) >> 16;
    uh = (uh + 0x7FFFu + ((uh >> 16) & 1u)) >> 16;
    return ul | (uh << 16);
}

// fp32 -> bf16 (RNE), vectorized: 16B in / 8B out per thread per iter.
__global__ void cvt_f32_to_bf16(const float4* __restrict__ in,
                                uint2* __restrict__ out, int n4) {
    int i = blockIdx.x * blockDim.x + threadIdx.x;
    const int stride = gridDim.x * blockDim.x;
    for (; i < n4; i += stride) {
        float4 a = in[i];
        uint2 o;
        o.x = pack2bf(a.x, a.y);
        o.y = pack2bf(a.z, a.w);
        out[i] = o;
    }
}

// Raw barrier + compiler-only memory fence (keeps loads/stores phase-pinned,
// leaves the instruction scheduler free).
#define BAR() do { __builtin_amdgcn_s_barrier(); \
                   asm volatile("" ::: "memory"); } while (0)

// ============================================================================
// READ-AHEAD 8-phase pipeline (fragment-register double buffering).
// Key fix vs r11 (which serialized LDS 576cyc + MFMA 620cyc per phase):
// ds_reads issued in phase p feed MFMA of phase p+1, so LDS data-return
// streams UNDER the MFMA cluster; one barrier per phase (8/iter, was 16).
//   phase body = [BAR][prefetch ds_reads (p+1)][stage half-tile][MFMA(p)]
// Staging (r11-verified): ph1 A(kb)h0  ph2 A(kb)h1  ph3 B(ka+2)h0
//   ph4 B(ka+2)h1  ph5 A(ka+2)h0  ph6 A(ka+2)h1  ph7 B(kb+2)h0  ph8 B(kb+2)h1
// vmcnt(2) at END of ph3/ph7 (ledger: drains A(kb),B(kb) resp. A,B(ka+2);
// 2 stay in flight) so the NEXT barrier publishes the landing to all waves
// before ph4/ph8's prefetch reads. vmcnt(0) at tail only.
// Correctness ledger (all verified by hand):
//  - every prefetch read is preceded by the vmcnt+barrier confirming its data;
//  - every staging write lands >=1 barrier after the region's last reader's
//    consuming MFMA (whose lgkm wait forces read completion).
// Geometry/swizzle/XCD map/epilogue identical to r6-r11 (absmax 2.0 verified).
// ============================================================================
__global__ __launch_bounds__(512, 2) void gemm_masked8(
    const unsigned short* __restrict__ Ab,   // x bf16 [M][K]
    const unsigned short* __restrict__ Bb,   // W bf16 [N][K]
    const float* __restrict__ X,             // x fp32 (mask)
    const float* __restrict__ Wt,            // W fp32 (mask)
    const float* __restrict__ bias,
    float* __restrict__ out)
{
    __shared__ __align__(16) char lds[131072];   // R0A|R0B|R1A|R1B x 32KB

    const int tid  = threadIdx.x;
    const int wave = tid >> 6;
    const int lane = tid & 63;
    const int lr = lane & 15;
    const int lq = lane >> 4;
    const int wm = wave >> 2;    // 0..1 : row half (128 rows)
    const int wn = wave & 3;     // 0..3 : 64-col slice

    // Concurrency-aware XCD cluster map (verified r6).
    const int flat = blockIdx.x;
    const int xcd  = flat & 7;
    const int s    = flat >> 3;            // 0..63
    const int rnd  = s >> 5;               // 0..1
    const int jj   = s & 31;               // 0..31
    const int trow = rnd * 16 + ((xcd >> 2) << 3) + (jj >> 2);   // 0..31
    const int tcol = ((xcd & 3) << 2) + (jj & 3);                // 0..15
    const int rowBase = trow * 256;
    const int colBase = tcol * 256;

    f32x4 acc[8][4];
    #pragma unroll
    for (int i = 0; i < 8; ++i)
        #pragma unroll
        for (int n = 0; n < 4; ++n)
            acc[i][n] = (f32x4){0.f, 0.f, 0.f, 0.f};

    // ---- staging (r6-verified): linear LDS dest; global col pre-swizzled --
    const int srow  = tid >> 3;                       // 0..63
    const int sslot = (tid & 7) ^ (srow & 7);
    const unsigned short* aSrc =
        Ab + (size_t)(rowBase + srow) * K_DIM + sslot * 8;
    const unsigned short* bSrc =
        Bb + (size_t)(colBase + srow) * K_DIM + sslot * 8;

    const unsigned R0A = 0, R0B = 32768, R1A = 65536, R1B = 98304;

    auto stageHalfA = [&](int kst, unsigned reg, int h) {
        #pragma unroll
        for (int i = 2 * h; i < 2 * h + 2; ++i)
            gload_lds16(aSrc + (size_t)i * 64 * K_DIM + kst * 64,
                        lds + reg + i * 8192 + wave * 1024);
    };
    auto stageHalfB = [&](int kst, unsigned reg, int h) {
        #pragma unroll
        for (int i = 2 * h; i < 2 * h + 2; ++i)
            gload_lds16(bSrc + (size_t)i * 64 * K_DIM + kst * 64,
                        lds + reg + i * 8192 + wave * 1024);
    };

    // ---- ds_read offsets (r6-verified swizzle) ----
    const unsigned kk0 = (unsigned)((lq) ^ (lr & 7)) * 16;
    const unsigned kk1 = (unsigned)((4 + lq) ^ (lr & 7)) * 16;
    const unsigned rowA = (unsigned)(wm * 128 + lr) * 128;   // + m*2048
    const unsigned rowB = (unsigned)(wn * 64 + lr) * 128;    // + nf*2048

    // Fragment register sets (all statically indexed).
    bf16x8 A0[4][2];      // A quad q0 of current K-step (loaded ph8/ph4)
    bf16x8 A1[4][2];      // A quad q1 (loaded ph2/ph6)
    bf16x8 B0R0[2][2];    // B nq0 for the R0 K-step (loaded ph8)
    bf16x8 B0R1[2][2];    // B nq0 for the R1 K-step (loaded ph4)
    bf16x8 B1[2][2];      // B nq1 (loaded ph1/ph5, consumed +1/+2)

    // ---- prologue: stage A(0),B(0)->R0, B(1)->R1B; preload ph1 operands ---
    stageHalfA(0, R0A, 0); stageHalfA(0, R0A, 1);
    stageHalfB(0, R0B, 0); stageHalfB(0, R0B, 1);
    stageHalfB(1, R1B, 0); stageHalfB(1, R1B, 1);
    asm volatile("s_waitcnt vmcnt(4)" ::: "memory");   // A0,B0 landed
    __builtin_amdgcn_s_barrier();
    asm volatile("" ::: "memory");
    #pragma unroll
    for (int m = 0; m < 4; ++m) {
        A0[m][0] = *(const bf16x8*)(lds + R0A + rowA + m * 2048 + kk0);
        A0[m][1] = *(const bf16x8*)(lds + R0A + rowA + m * 2048 + kk1);
    }
    #pragma unroll
    for (int n = 0; n < 2; ++n) {
        B0R0[n][0] = *(const bf16x8*)(lds + R0B + rowB + n * 2048 + kk0);
        B0R0[n][1] = *(const bf16x8*)(lds + R0B + rowB + n * 2048 + kk1);
    }

    #define MFMA_QUAD(ACC_M, ACC_N, AREG, BREG)                                \
        do {                                                                   \
            __builtin_amdgcn_s_setprio(1);                                     \
            _Pragma("unroll")                                                  \
            for (int m = 0; m < 4; ++m)                                        \
                _Pragma("unroll")                                              \
                for (int n = 0; n < 2; ++n)                                    \
                    _Pragma("unroll")                                          \
                    for (int ks = 0; ks < 2; ++ks)                             \
                        acc[(ACC_M) + m][(ACC_N) + n] =                        \
                            __builtin_amdgcn_mfma_f32_16x16x32_bf16(           \
                                AREG[m][ks], BREG[n][ks],                      \
                                acc[(ACC_M) + m][(ACC_N) + n], 0, 0, 0);       \
            __builtin_amdgcn_s_setprio(0);                                     \
        } while (0)

    for (int j = 0; j < NIT; ++j) {
        const int ka = 2 * j;
        const int kb = 2 * j + 1;
        const bool stg = (j + 1 < NIT);

        // ---- ph1: prefetch B1<-R0B nq1; stage A(kb)h0->R1A; MFMA(mq0,nq0) --
        BAR();
        #pragma unroll
        for (int n = 0; n < 2; ++n) {
            B1[n][0] = *(const bf16x8*)(lds + R0B + rowB + (2 + n) * 2048 + kk0);
            B1[n][1] = *(const bf16x8*)(lds + R0B + rowB + (2 + n) * 2048 + kk1);
        }
        stageHalfA(kb, R1A, 0);
        MFMA_QUAD(0, 0, A0, B0R0);

        // ---- ph2: prefetch A1<-R0A q1; stage A(kb)h1; MFMA(mq0,nq1) ----
        BAR();
        #pragma unroll
        for (int m = 0; m < 4; ++m) {
            A1[m][0] = *(const bf16x8*)(lds + R0A + rowA + (4 + m) * 2048 + kk0);
            A1[m][1] = *(const bf16x8*)(lds + R0A + rowA + (4 + m) * 2048 + kk1);
        }
        stageHalfA(kb, R1A, 1);
        MFMA_QUAD(0, 2, A0, B1);

        // ---- ph3: stage B(ka+2)h0; MFMA(mq1,nq1); vmcnt confirms A,B(kb) --
        BAR();
        if (stg) stageHalfB(ka + 2, R0B, 0);
        MFMA_QUAD(4, 2, A1, B1);
        if (stg) asm volatile("s_waitcnt vmcnt(2)" ::: "memory");
        else     asm volatile("s_waitcnt vmcnt(0)" ::: "memory");

        // ---- ph4: prefetch A0<-R1A q0, B0R1<-R1B nq0; stage B(ka+2)h1;
        //           MFMA(mq1,nq0) ----
        BAR();
        #pragma unroll
        for (int m = 0; m < 4; ++m) {
            A0[m][0] = *(const bf16x8*)(lds + R1A + rowA + m * 2048 + kk0);
            A0[m][1] = *(const bf16x8*)(lds + R1A + rowA + m * 2048 + kk1);
        }
        #pragma unroll
        for (int n = 0; n < 2; ++n) {
            B0R1[n][0] = *(const bf16x8*)(lds + R1B + rowB + n * 2048 + kk0);
            B0R1[n][1] = *(const bf16x8*)(lds + R1B + rowB + n * 2048 + kk1);
        }
        if (stg) stageHalfB(ka + 2, R0B, 1);
        MFMA_QUAD(4, 0, A1, B0R0);

        // ---- ph5: prefetch B1<-R1B nq1; stage A(ka+2)h0->R0A; MFMA(mq0,nq0)
        BAR();
        #pragma unroll
        for (int n = 0; n < 2; ++n) {
            B1[n][0] = *(const bf16x8*)(lds + R1B + rowB + (2 + n) * 2048 + kk0);
            B1[n][1] = *(const bf16x8*)(lds + R1B + rowB + (2 + n) * 2048 + kk1);
        }
        if (stg) stageHalfA(ka + 2, R0A, 0);
        MFMA_QUAD(0, 0, A0, B0R1);

        // ---- ph6: prefetch A1<-R1A q1; stage A(ka+2)h1; MFMA(mq0,nq1) ----
        BAR();
        #pragma unroll
        for (int m = 0; m < 4; ++m) {
            A1[m][0] = *(const bf16x8*)(lds + R1A + rowA + (4 + m) * 2048 + kk0);
            A1[m][1] = *(const bf16x8*)(lds + R1A + rowA + (4 + m) * 2048 + kk1);
        }
        if (stg) stageHalfA(ka + 2, R0A, 1);
        MFMA_QUAD(0, 2, A0, B1);

        // ---- ph7: stage B(kb+2)h0->R1B; MFMA(mq1,nq1); vmcnt A,B(ka+2) ----
        BAR();
        if (stg) stageHalfB(kb + 2, R1B, 0);
        MFMA_QUAD(4, 2, A1, B1);
        if (stg) asm volatile("s_waitcnt vmcnt(2)" ::: "memory");
        else     asm volatile("s_waitcnt vmcnt(0)" ::: "memory");

        // ---- ph8: prefetch A0<-R0A q0, B0R0<-R0B nq0 (next iter); stage
        //           B(kb+2)h1; MFMA(mq1,nq0) ----
        BAR();
        if (stg) {
            #pragma unroll
            for (int m = 0; m < 4; ++m) {
                A0[m][0] = *(const bf16x8*)(lds + R0A + rowA + m * 2048 + kk0);
                A0[m][1] = *(const bf16x8*)(lds + R0A + rowA + m * 2048 + kk1);
            }
            #pragma unroll
            for (int n = 0; n < 2; ++n) {
                B0R0[n][0] = *(const bf16x8*)(lds + R0B + rowB + n * 2048 + kk0);
                B0R0[n][1] = *(const bf16x8*)(lds + R0B + rowB + n * 2048 + kk1);
            }
            stageHalfB(kb + 2, R1B, 1);
        }
        MFMA_QUAD(4, 0, A1, B0R1);
    }

    // ---- epilogue: bit-exact fp32 mask + bias + store (verified r3-r11) ---
    __syncthreads();
    float* x0s = (float*)(lds);            // [256][16] f32, 16KB
    float* w0s = (float*)(lds + 16384);    // [256][16] f32
    #pragma unroll
    for (int i = 0; i < 2; ++i) {
        int idx = tid + i * 512;           // 1024 float4 slots
        int r = idx >> 2, qq = (idx & 3) << 2;
        *(f32x4*)(x0s + r * 16 + qq) =
            *(const f32x4*)(X + (size_t)(rowBase + r) * K_DIM + qq);
        *(f32x4*)(w0s + r * 16 + qq) =
            *(const f32x4*)(Wt + (size_t)(colBase + r) * K_DIM + qq);
    }
    __syncthreads();

    const float TAU32 = (float)TAU_D;

    #pragma unroll
    for (int np = 0; np < 4; np += 2) {
        float wv[2][16];
        float bv[2];
        #pragma unroll
        for (int e = 0; e < 2; ++e) {
            const int c = wn * 64 + (np + e) * 16 + lr;
            #pragma unroll
            for (int q = 0; q < 4; ++q)
                *(f32x4*)&wv[e][q * 4] = *(const f32x4*)(w0s + c * 16 + q * 4);
            bv[e] = bias[colBase + c];
        }
        #pragma unroll
        for (int mi = 0; mi < 8; ++mi) {
            #pragma unroll
            for (int jr = 0; jr < 4; ++jr) {
                const int rw = wm * 128 + mi * 16 + lq * 4 + jr;
                float xv[16];
                #pragma unroll
                for (int q = 0; q < 4; ++q)
                    *(f32x4*)&xv[q * 4] = *(const f32x4*)(x0s + rw * 16 + q * 4);
                const size_t orow = (size_t)(rowBase + rw) * N_DIM + colBase;
                #pragma unroll
                for (int e = 0; e < 2; ++e) {
                    const int n = np + e;
                    float y1 = 0.f, s2 = 0.f;
                    #pragma unroll
                    for (int k = 0; k < 16; ++k) {
                        float xk = xv[k], wk = wv[e][k];
                        float xx = xk * xk, ww = wk * wk;
                        y1 = fmaf(xk, wk, y1);
                        s2 = fmaf(xx, ww, s2);
                    }
                    float t = fabsf(y1) / sqrtf(s2 * 0.0625f);
                    float v = (t < TAU32) ? 0.0f : (acc[mi][n][jr] + bv[e]);
                    out[orow + wn * 64 + n * 16 + lr] = v;
                }
            }
        }
    }
}

// ============================================================================
// Fallback (no workspace): round-3 verified 128x128 kernel, reg-staged cvt.
// ============================================================================
__global__ __launch_bounds__(256, 2) void gemm_masked_fb(
    const float* __restrict__ X, const float* __restrict__ Wt,
    const float* __restrict__ bias, float* __restrict__ out)
{
    __shared__ __align__(16) unsigned short As[128 * 32];
    __shared__ __align__(16) unsigned short Bs[128 * 32];

    const int tid  = threadIdx.x;
    const int wave = tid >> 6;
    const int lane = tid & 63;
    const int rowBase = blockIdx.y * 128;
    const int colBase = blockIdx.x * 128;
    const int wr = wave >> 1;
    const int wc = wave & 1;
    const int lr = lane & 15;
    const int lq = lane >> 4;

    f32x4 acc[4][4];
    #pragma unroll
    for (int m = 0; m < 4; ++m)
        #pragma unroll
        for (int n = 0; n < 4; ++n)
            acc[m][n] = (f32x4){0.f, 0.f, 0.f, 0.f};

    const int srow = tid >> 2;
    const int scol = (tid & 3) * 8;
    const float* afp = X  + (size_t)(rowBase + srow) * K_DIM + scol;
    const float* bfp = Wt + (size_t)(colBase + srow) * K_DIM + scol;

    for (int kt = 0; kt < K_DIM; kt += 32) {
        #pragma unroll
        for (int issue = 0; issue < 2; ++issue) {
            const float* sa = afp + (size_t)issue * 64 * K_DIM;
            const float* sb = bfp + (size_t)issue * 64 * K_DIM;
            float4 a0 = *(const float4*)(sa);
            float4 a1 = *(const float4*)(sa + 4);
            float4 b0 = *(const float4*)(sb);
            float4 b1 = *(const float4*)(sb + 4);
            uint4 pa, pb;
            pa.x = pack2bf(a0.x, a0.y); pa.y = pack2bf(a0.z, a0.w);
            pa.z = pack2bf(a1.x, a1.y); pa.w = pack2bf(a1.z, a1.w);
            pb.x = pack2bf(b0.x, b0.y); pb.y = pack2bf(b0.z, b0.w);
            pb.z = pack2bf(b1.x, b1.y); pb.w = pack2bf(b1.z, b1.w);
            *(uint4*)((char*)As + issue * 4096 + tid * 16) = pa;
            *(uint4*)((char*)Bs + issue * 4096 + tid * 16) = pb;
        }
        afp += 32; bfp += 32;
        __syncthreads();

        bf16x8 af[4], bq[4];
        #pragma unroll
        for (int m = 0; m < 4; ++m)
            af[m] = *(const bf16x8*)(As + (wr * 64 + m * 16 + lr) * 32 + lq * 8);
        #pragma unroll
        for (int n = 0; n < 4; ++n)
            bq[n] = *(const bf16x8*)(Bs + (wc * 64 + n * 16 + lr) * 32 + lq * 8);
        #pragma unroll
        for (int m = 0; m < 4; ++m)
            #pragma unroll
            for (int n = 0; n < 4; ++n)
                acc[m][n] = __builtin_amdgcn_mfma_f32_16x16x32_bf16(
                    af[m], bq[n], acc[m][n], 0, 0, 0);
        __syncthreads();
    }

    float* x0s = (float*)As;
    float* w0s = (float*)Bs;
    #pragma unroll
    for (int i = 0; i < 2; ++i) {
        int idx = tid + i * 256;
        int r = idx >> 2, q = (idx & 3) * 4;
        *(float4*)(x0s + r * 16 + q) =
            *(const float4*)(X + (size_t)(rowBase + r) * K_DIM + q);
        *(float4*)(w0s + r * 16 + q) =
            *(const float4*)(Wt + (size_t)(colBase + r) * K_DIM + q);
    }
    __syncthreads();

    const float TAU32 = (float)TAU_D;
    float wv[4][16];
    float bv[4];
    #pragma unroll
    for (int n = 0; n < 4; ++n) {
        int c = wc * 64 + n * 16 + lr;
        #pragma unroll
        for (int q = 0; q < 4; ++q)
            *(f32x4*)&wv[n][q * 4] = *(const f32x4*)(w0s + c * 16 + q * 4);
        bv[n] = bias[colBase + c];
    }

    #pragma unroll
    for (int m = 0; m < 4; ++m) {
        #pragma unroll
        for (int j = 0; j < 4; ++j) {
            const int r = wr * 64 + m * 16 + lq * 4 + j;
            float xv[16];
            #pragma unroll
            for (int q = 0; q < 4; ++q)
                *(f32x4*)&xv[q * 4] = *(const f32x4*)(x0s + r * 16 + q * 4);
            const size_t orow = (size_t)(rowBase + r) * N_DIM + colBase;
            #pragma unroll
            for (int n = 0; n < 4; ++n) {
                float y1 = 0.f, s2 = 0.f;
                #pragma unroll
                for (int k = 0; k < 16; ++k) {
                    float xk = xv[k];
                    float wk = wv[n][k];
                    float xx = xk * xk;
                    float ww = wk * wk;
                    y1 = fmaf(xk, wk, y1);
                    s2 = fmaf(xx, ww, s2);
                }
                float t = fabsf(y1) / sqrtf(s2 * 0.0625f);
                float v = (t < TAU32) ? 0.0f : (acc[m][n][j] + bv[n]);
                out[orow + wc * 64 + n * 16 + lr] = v;
            }
        }
    }
}

extern "C" void kernel_launch(void* const* d_in, const int* in_sizes, int n_in,
                              void* d_out, int out_size, void* d_ws, size_t ws_size,
                              hipStream_t stream) {
    const float* x    = (const float*)d_in[0];
    const float* W    = (const float*)d_in[1];
    const float* bias = (const float*)d_in[2];
    float* out = (float*)d_out;

    const size_t needA = (size_t)M_DIM * K_DIM * 2;   // 64 MB
    const size_t needB = (size_t)N_DIM * K_DIM * 2;   // 32 MB

    if (ws_size >= needA + needB) {
        unsigned short* xb = (unsigned short*)d_ws;
        unsigned short* wb = (unsigned short*)((char*)d_ws + needA);
        cvt_f32_to_bf16<<<2048, 256, 0, stream>>>(
            (const float4*)x, (uint2*)xb, (M_DIM * K_DIM) / 4);
        cvt_f32_to_bf16<<<2048, 256, 0, stream>>>(
            (const float4*)W, (uint2*)wb, (N_DIM * K_DIM) / 4);
        dim3 grid((M_DIM / 256) * (N_DIM / 256));     // 512 blocks, 1-D
        gemm_masked8<<<grid, 512, 0, stream>>>(xb, wb, x, W, bias, out);
    } else {
        dim3 grid(N_DIM / 128, M_DIM / 128);
        gemm_masked_fb<<<grid, 256, 0, stream>>>(x, W, bias, out);
    }
}

// Round 13
// 312.111 us; speedup vs baseline: 1.0359x; 1.0359x over previous
//
#include <hip/hip_runtime.h>
#include <cstdint>
#include <cstddef>

#define TAU_D 2.053748910631823
#define M_DIM 8192
#define N_DIM 4096
#define K_DIM 4096
#define NIT   32               // iterations; each covers 2 K-steps of BK=64

typedef float f32x4  __attribute__((ext_vector_type(4)));
typedef short bf16x8 __attribute__((ext_vector_type(8)));

typedef __attribute__((address_space(1))) void gvoid_t;
typedef __attribute__((address_space(3))) void lvoid_t;

__device__ __forceinline__ void gload_lds16(const void* g, void* l) {
    __builtin_amdgcn_global_load_lds((const gvoid_t*)g, (lvoid_t*)l, 16, 0, 0);
}

__device__ __forceinline__ unsigned int pack2bf(float lo, float hi) {
    unsigned int ul = __float_as_uint(lo);
    unsigned int uh = __float_as_uint(hi);
    ul = (ul + 0x7FFFu + ((ul >> 16) & 1u)) >> 16;
    uh = (uh + 0x7FFFu + ((uh >> 16) & 1u)) >> 16;
    return ul | (uh << 16);
}

// fp32 -> bf16 (RNE), vectorized: 16B in / 8B out per thread per iter.
__global__ void cvt_f32_to_bf16(const float4* __restrict__ in,
                                uint2* __restrict__ out, int n4) {
    int i = blockIdx.x * blockDim.x + threadIdx.x;
    const int stride = gridDim.x * blockDim.x;
    for (; i < n4; i += stride) {
        float4 a = in[i];
        uint2 o;
        o.x = pack2bf(a.x, a.y);
        o.y = pack2bf(a.z, a.w);
        out[i] = o;
    }
}

// Raw barrier + compiler-only memory fence (keeps memory ops phase-pinned,
// leaves the instruction scheduler free -- m141 lesson).
#define BAR() do { __builtin_amdgcn_s_barrier(); \
                   asm volatile("" ::: "memory"); } while (0)

// ============================================================================
// r11 structure with ONE barrier per phase (8/iter, was 16).
// Hazard proof for the merged structure: phase body = [BAR][reads][stage]
// [MFMA]. (a) reads(p) target regions whose staging was confirmed by a
// previous vmcnt + BAR; (b) stage(p) writes a region whose last reader
// completed its ds_reads before its own MFMA (compiler lgkmcnt) and hence
// before passing the BAR at top of phase p -- one barrier suffices for WAR;
// (c) MFMA(p) depends on reads(p) via registers (auto lgkmcnt), no barrier
// needed between them.
// Staging + vmcnt ledger identical to r11 (hand-verified, absmax 2.0):
//   ph1 A(kb)h0->R1A   ph2 A(kb)h1->R1A   ph3 B(ka+2)h0->R0B
//   ph4 B(ka+2)h1->R0B [vmcnt(4)]         ph5 A(ka+2)h0->R0A
//   ph6 A(ka+2)h1->R0A ph7 B(kb+2)h0->R1B ph8 B(kb+2)h1->R1B [vmcnt(4)]
// vmcnt(4)@ph4: forces B(kb),A(kb) landed (needed ph5-8); B(ka+2) flies.
// vmcnt(4)@ph8: forces B(ka+2),A(ka+2) landed (needed next ph1-4).
// Geometry/swizzle/XCD map/epilogue identical to r6-r11 (absmax 2.0).
// ============================================================================
__global__ __launch_bounds__(512, 2) void gemm_masked8(
    const unsigned short* __restrict__ Ab,   // x bf16 [M][K]
    const unsigned short* __restrict__ Bb,   // W bf16 [N][K]
    const float* __restrict__ X,             // x fp32 (mask)
    const float* __restrict__ Wt,            // W fp32 (mask)
    const float* __restrict__ bias,
    float* __restrict__ out)
{
    __shared__ __align__(16) char lds[131072];   // R0A|R0B|R1A|R1B x 32KB

    const int tid  = threadIdx.x;
    const int wave = tid >> 6;
    const int lane = tid & 63;
    const int lr = lane & 15;
    const int lq = lane >> 4;
    const int wm = wave >> 2;    // 0..1 : row half (128 rows)
    const int wn = wave & 3;     // 0..3 : 64-col slice

    // Concurrency-aware XCD cluster map (verified r6).
    const int flat = blockIdx.x;
    const int xcd  = flat & 7;
    const int s    = flat >> 3;            // 0..63
    const int rnd  = s >> 5;               // 0..1
    const int jj   = s & 31;               // 0..31
    const int trow = rnd * 16 + ((xcd >> 2) << 3) + (jj >> 2);   // 0..31
    const int tcol = ((xcd & 3) << 2) + (jj & 3);                // 0..15
    const int rowBase = trow * 256;
    const int colBase = tcol * 256;

    f32x4 acc[8][4];
    #pragma unroll
    for (int i = 0; i < 8; ++i)
        #pragma unroll
        for (int n = 0; n < 4; ++n)
            acc[i][n] = (f32x4){0.f, 0.f, 0.f, 0.f};

    // ---- staging (r6-verified): linear LDS dest; global col pre-swizzled --
    const int srow  = tid >> 3;                       // 0..63
    const int sslot = (tid & 7) ^ (srow & 7);
    const unsigned short* aSrc =
        Ab + (size_t)(rowBase + srow) * K_DIM + sslot * 8;
    const unsigned short* bSrc =
        Bb + (size_t)(colBase + srow) * K_DIM + sslot * 8;

    const unsigned R0A = 0, R0B = 32768, R1A = 65536, R1B = 98304;

    auto stageHalfA = [&](int kst, unsigned reg, int h) {
        #pragma unroll
        for (int i = 2 * h; i < 2 * h + 2; ++i)
            gload_lds16(aSrc + (size_t)i * 64 * K_DIM + kst * 64,
                        lds + reg + i * 8192 + wave * 1024);
    };
    auto stageHalfB = [&](int kst, unsigned reg, int h) {
        #pragma unroll
        for (int i = 2 * h; i < 2 * h + 2; ++i)
            gload_lds16(bSrc + (size_t)i * 64 * K_DIM + kst * 64,
                        lds + reg + i * 8192 + wave * 1024);
    };

    // ---- ds_read offsets (r6-verified swizzle) ----
    const unsigned kk0 = (unsigned)((lq) ^ (lr & 7)) * 16;
    const unsigned kk1 = (unsigned)((4 + lq) ^ (lr & 7)) * 16;
    const unsigned rowA = (unsigned)(wm * 128 + lr) * 128;   // + m*2048
    const unsigned rowB = (unsigned)(wn * 64 + lr) * 128;    // + nf*2048

    // ---- prologue: A(0),B(0)->R0; B(1)->R1B; per-wave vmcnt; ph1 BAR syncs.
    stageHalfA(0, R0A, 0); stageHalfA(0, R0A, 1);
    stageHalfB(0, R0B, 0); stageHalfB(0, R0B, 1);
    stageHalfB(1, R1B, 0); stageHalfB(1, R1B, 1);
    asm volatile("s_waitcnt vmcnt(4)" ::: "memory");   // A0,B0 landed

    bf16x8 aF[4][2];     // A quadrant (q0 lives ph1-2 / q1 ph3-4; reloaded)
    bf16x8 bF0[2][2];    // B nq0 (lives ph1..ph4 of its K-step)
    bf16x8 bF1[2][2];    // B nq1 (lives ph2..ph3)

    #define MFMA_QUAD(ACC_M, ACC_N, BREG)                                      \
        do {                                                                   \
            __builtin_amdgcn_s_setprio(1);                                     \
            _Pragma("unroll")                                                  \
            for (int m = 0; m < 4; ++m)                                        \
                _Pragma("unroll")                                              \
                for (int n = 0; n < 2; ++n)                                    \
                    _Pragma("unroll")                                          \
                    for (int ks = 0; ks < 2; ++ks)                             \
                        acc[(ACC_M) + m][(ACC_N) + n] =                        \
                            __builtin_amdgcn_mfma_f32_16x16x32_bf16(           \
                                aF[m][ks], BREG[n][ks],                        \
                                acc[(ACC_M) + m][(ACC_N) + n], 0, 0, 0);       \
            __builtin_amdgcn_s_setprio(0);                                     \
        } while (0)

    for (int j = 0; j < NIT; ++j) {
        const int ka = 2 * j;
        const int kb = 2 * j + 1;
        const bool stg = (j + 1 < NIT);

        // ---- ph1: reads A q0 + B nq0 (R0); stage A(kb)h0->R1A; MFMA ----
        BAR();
        #pragma unroll
        for (int m = 0; m < 4; ++m) {
            aF[m][0] = *(const bf16x8*)(lds + R0A + rowA + m * 2048 + kk0);
            aF[m][1] = *(const bf16x8*)(lds + R0A + rowA + m * 2048 + kk1);
        }
        #pragma unroll
        for (int n = 0; n < 2; ++n) {
            bF0[n][0] = *(const bf16x8*)(lds + R0B + rowB + n * 2048 + kk0);
            bF0[n][1] = *(const bf16x8*)(lds + R0B + rowB + n * 2048 + kk1);
        }
        stageHalfA(kb, R1A, 0);
        MFMA_QUAD(0, 0, bF0);

        // ---- ph2: reads B nq1 (R0); stage A(kb)h1->R1A; MFMA ----
        BAR();
        #pragma unroll
        for (int n = 0; n < 2; ++n) {
            bF1[n][0] = *(const bf16x8*)(lds + R0B + rowB + (2 + n) * 2048 + kk0);
            bF1[n][1] = *(const bf16x8*)(lds + R0B + rowB + (2 + n) * 2048 + kk1);
        }
        stageHalfA(kb, R1A, 1);
        MFMA_QUAD(0, 2, bF1);

        // ---- ph3: reads A q1 (R0); stage B(ka+2)h0->R0B; MFMA ----
        BAR();
        #pragma unroll
        for (int m = 0; m < 4; ++m) {
            aF[m][0] = *(const bf16x8*)(lds + R0A + rowA + (4 + m) * 2048 + kk0);
            aF[m][1] = *(const bf16x8*)(lds + R0A + rowA + (4 + m) * 2048 + kk1);
        }
        if (stg) stageHalfB(ka + 2, R0B, 0);
        MFMA_QUAD(4, 2, bF1);

        // ---- ph4: stage B(ka+2)h1->R0B; MFMA; counted vmcnt ----
        BAR();
        if (stg) stageHalfB(ka + 2, R0B, 1);
        MFMA_QUAD(4, 0, bF0);
        if (stg) asm volatile("s_waitcnt vmcnt(4)" ::: "memory");
        else     asm volatile("s_waitcnt vmcnt(0)" ::: "memory");

        // ---- ph5: reads A q0 + B nq0 (R1); stage A(ka+2)h0->R0A; MFMA ----
        BAR();
        #pragma unroll
        for (int m = 0; m < 4; ++m) {
            aF[m][0] = *(const bf16x8*)(lds + R1A + rowA + m * 2048 + kk0);
            aF[m][1] = *(const bf16x8*)(lds + R1A + rowA + m * 2048 + kk1);
        }
        #pragma unroll
        for (int n = 0; n < 2; ++n) {
            bF0[n][0] = *(const bf16x8*)(lds + R1B + rowB + n * 2048 + kk0);
            bF0[n][1] = *(const bf16x8*)(lds + R1B + rowB + n * 2048 + kk1);
        }
        if (stg) stageHalfA(ka + 2, R0A, 0);
        MFMA_QUAD(0, 0, bF0);

        // ---- ph6: reads B nq1 (R1); stage A(ka+2)h1->R0A; MFMA ----
        BAR();
        #pragma unroll
        for (int n = 0; n < 2; ++n) {
            bF1[n][0] = *(const bf16x8*)(lds + R1B + rowB + (2 + n) * 2048 + kk0);
            bF1[n][1] = *(const bf16x8*)(lds + R1B + rowB + (2 + n) * 2048 + kk1);
        }
        if (stg) stageHalfA(ka + 2, R0A, 1);
        MFMA_QUAD(0, 2, bF1);

        // ---- ph7: reads A q1 (R1); stage B(kb+2)h0->R1B; MFMA ----
        BAR();
        #pragma unroll
        for (int m = 0; m < 4; ++m) {
            aF[m][0] = *(const bf16x8*)(lds + R1A + rowA + (4 + m) * 2048 + kk0);
            aF[m][1] = *(const bf16x8*)(lds + R1A + rowA + (4 + m) * 2048 + kk1);
        }
        if (stg) stageHalfB(kb + 2, R1B, 0);
        MFMA_QUAD(4, 2, bF1);

        // ---- ph8: stage B(kb+2)h1->R1B; MFMA; counted vmcnt ----
        BAR();
        if (stg) stageHalfB(kb + 2, R1B, 1);
        MFMA_QUAD(4, 0, bF0);
        if (stg) asm volatile("s_waitcnt vmcnt(4)" ::: "memory");
    }

    // ---- epilogue: bit-exact fp32 mask + bias + store (verified r3-r12) ---
    __syncthreads();
    float* x0s = (float*)(lds);            // [256][16] f32, 16KB
    float* w0s = (float*)(lds + 16384);    // [256][16] f32
    #pragma unroll
    for (int i = 0; i < 2; ++i) {
        int idx = tid + i * 512;           // 1024 float4 slots
        int r = idx >> 2, qq = (idx & 3) << 2;
        *(f32x4*)(x0s + r * 16 + qq) =
            *(const f32x4*)(X + (size_t)(rowBase + r) * K_DIM + qq);
        *(f32x4*)(w0s + r * 16 + qq) =
            *(const f32x4*)(Wt + (size_t)(colBase + r) * K_DIM + qq);
    }
    __syncthreads();

    const float TAU32 = (float)TAU_D;

    // n in adjacent pairs: both 64B halves of each 128B output line stored
    // back-to-back (write-amplification fix, verified r6-r12).
    #pragma unroll
    for (int np = 0; np < 4; np += 2) {
        float wv[2][16];
        float bv[2];
        #pragma unroll
        for (int e = 0; e < 2; ++e) {
            const int c = wn * 64 + (np + e) * 16 + lr;
            #pragma unroll
            for (int q = 0; q < 4; ++q)
                *(f32x4*)&wv[e][q * 4] = *(const f32x4*)(w0s + c * 16 + q * 4);
            bv[e] = bias[colBase + c];
        }
        #pragma unroll
        for (int mi = 0; mi < 8; ++mi) {
            #pragma unroll
            for (int jr = 0; jr < 4; ++jr) {
                const int rw = wm * 128 + mi * 16 + lq * 4 + jr;
                float xv[16];
                #pragma unroll
                for (int q = 0; q < 4; ++q)
                    *(f32x4*)&xv[q * 4] = *(const f32x4*)(x0s + rw * 16 + q * 4);
                const size_t orow = (size_t)(rowBase + rw) * N_DIM + colBase;
                #pragma unroll
                for (int e = 0; e < 2; ++e) {
                    const int n = np + e;
                    // Replicate BLAS sgemm: single-acc fma chain, k ascending.
                    float y1 = 0.f, s2 = 0.f;
                    #pragma unroll
                    for (int k = 0; k < 16; ++k) {
                        float xk = xv[k], wk = wv[e][k];
                        float xx = xk * xk, ww = wk * wk;
                        y1 = fmaf(xk, wk, y1);
                        s2 = fmaf(xx, ww, s2);
                    }
                    float t = fabsf(y1) / sqrtf(s2 * 0.0625f);
                    float v = (t < TAU32) ? 0.0f : (acc[mi][n][jr] + bv[e]);
                    out[orow + wn * 64 + n * 16 + lr] = v;
                }
            }
        }
    }
}

// ============================================================================
// Fallback (no workspace): round-3 verified 128x128 kernel, reg-staged cvt.
// ============================================================================
__global__ __launch_bounds__(256, 2) void gemm_masked_fb(
    const float* __restrict__ X, const float* __restrict__ Wt,
    const float* __restrict__ bias, float* __restrict__ out)
{
    __shared__ __align__(16) unsigned short As[128 * 32];
    __shared__ __align__(16) unsigned short Bs[128 * 32];

    const int tid  = threadIdx.x;
    const int wave = tid >> 6;
    const int lane = tid & 63;
    const int rowBase = blockIdx.y * 128;
    const int colBase = blockIdx.x * 128;
    const int wr = wave >> 1;
    const int wc = wave & 1;
    const int lr = lane & 15;
    const int lq = lane >> 4;

    f32x4 acc[4][4];
    #pragma unroll
    for (int m = 0; m < 4; ++m)
        #pragma unroll
        for (int n = 0; n < 4; ++n)
            acc[m][n] = (f32x4){0.f, 0.f, 0.f, 0.f};

    const int srow = tid >> 2;
    const int scol = (tid & 3) * 8;
    const float* afp = X  + (size_t)(rowBase + srow) * K_DIM + scol;
    const float* bfp = Wt + (size_t)(colBase + srow) * K_DIM + scol;

    for (int kt = 0; kt < K_DIM; kt += 32) {
        #pragma unroll
        for (int issue = 0; issue < 2; ++issue) {
            const float* sa = afp + (size_t)issue * 64 * K_DIM;
            const float* sb = bfp + (size_t)issue * 64 * K_DIM;
            float4 a0 = *(const float4*)(sa);
            float4 a1 = *(const float4*)(sa + 4);
            float4 b0 = *(const float4*)(sb);
            float4 b1 = *(const float4*)(sb + 4);
            uint4 pa, pb;
            pa.x = pack2bf(a0.x, a0.y); pa.y = pack2bf(a0.z, a0.w);
            pa.z = pack2bf(a1.x, a1.y); pa.w = pack2bf(a1.z, a1.w);
            pb.x = pack2bf(b0.x, b0.y); pb.y = pack2bf(b0.z, b0.w);
            pb.z = pack2bf(b1.x, b1.y); pb.w = pack2bf(b1.z, b1.w);
            *(uint4*)((char*)As + issue * 4096 + tid * 16) = pa;
            *(uint4*)((char*)Bs + issue * 4096 + tid * 16) = pb;
        }
        afp += 32; bfp += 32;
        __syncthreads();

        bf16x8 af[4], bq[4];
        #pragma unroll
        for (int m = 0; m < 4; ++m)
            af[m] = *(const bf16x8*)(As + (wr * 64 + m * 16 + lr) * 32 + lq * 8);
        #pragma unroll
        for (int n = 0; n < 4; ++n)
            bq[n] = *(const bf16x8*)(Bs + (wc * 64 + n * 16 + lr) * 32 + lq * 8);
        #pragma unroll
        for (int m = 0; m < 4; ++m)
            #pragma unroll
            for (int n = 0; n < 4; ++n)
                acc[m][n] = __builtin_amdgcn_mfma_f32_16x16x32_bf16(
                    af[m], bq[n], acc[m][n], 0, 0, 0);
        __syncthreads();
    }

    float* x0s = (float*)As;
    float* w0s = (float*)Bs;
    #pragma unroll
    for (int i = 0; i < 2; ++i) {
        int idx = tid + i * 256;
        int r = idx >> 2, q = (idx & 3) * 4;
        *(float4*)(x0s + r * 16 + q) =
            *(const float4*)(X + (size_t)(rowBase + r) * K_DIM + q);
        *(float4*)(w0s + r * 16 + q) =
            *(const float4*)(Wt + (size_t)(colBase + r) * K_DIM + q);
    }
    __syncthreads();

    const float TAU32 = (float)TAU_D;
    float wv[4][16];
    float bv[4];
    #pragma unroll
    for (int n = 0; n < 4; ++n) {
        int c = wc * 64 + n * 16 + lr;
        #pragma unroll
        for (int q = 0; q < 4; ++q)
            *(f32x4*)&wv[n][q * 4] = *(const f32x4*)(w0s + c * 16 + q * 4);
        bv[n] = bias[colBase + c];
    }

    #pragma unroll
    for (int m = 0; m < 4; ++m) {
        #pragma unroll
        for (int j = 0; j < 4; ++j) {
            const int r = wr * 64 + m * 16 + lq * 4 + j;
            float xv[16];
            #pragma unroll
            for (int q = 0; q < 4; ++q)
                *(f32x4*)&xv[q * 4] = *(const f32x4*)(x0s + r * 16 + q * 4);
            const size_t orow = (size_t)(rowBase + r) * N_DIM + colBase;
            #pragma unroll
            for (int n = 0; n < 4; ++n) {
                float y1 = 0.f, s2 = 0.f;
                #pragma unroll
                for (int k = 0; k < 16; ++k) {
                    float xk = xv[k];
                    float wk = wv[n][k];
                    float xx = xk * xk;
                    float ww = wk * wk;
                    y1 = fmaf(xk, wk, y1);
                    s2 = fmaf(xx, ww, s2);
                }
                float t = fabsf(y1) / sqrtf(s2 * 0.0625f);
                float v = (t < TAU32) ? 0.0f : (acc[m][n][j] + bv[n]);
                out[orow + wc * 64 + n * 16 + lr] = v;
            }
        }
    }
}

extern "C" void kernel_launch(void* const* d_in, const int* in_sizes, int n_in,
                              void* d_out, int out_size, void* d_ws, size_t ws_size,
                              hipStream_t stream) {
    const float* x    = (const float*)d_in[0];
    const float* W    = (const float*)d_in[1];
    const float* bias = (const float*)d_in[2];
    float* out = (float*)d_out;

    const size_t needA = (size_t)M_DIM * K_DIM * 2;   // 64 MB
    const size_t needB = (size_t)N_DIM * K_DIM * 2;   // 32 MB

    if (ws_size >= needA + needB) {
        unsigned short* xb = (unsigned short*)d_ws;
        unsigned short* wb = (unsigned short*)((char*)d_ws + needA);
        cvt_f32_to_bf16<<<2048, 256, 0, stream>>>(
            (const float4*)x, (uint2*)xb, (M_DIM * K_DIM) / 4);
        cvt_f32_to_bf16<<<2048, 256, 0, stream>>>(
            (const float4*)W, (uint2*)wb, (N_DIM * K_DIM) / 4);
        dim3 grid((M_DIM / 256) * (N_DIM / 256));     // 512 blocks, 1-D
        gemm_masked8<<<grid, 512, 0, stream>>>(xb, wb, x, W, bias, out);
    } else {
        dim3 grid(N_DIM / 128, M_DIM / 128);
        gemm_masked_fb<<<grid, 256, 0, stream>>>(x, W, bias, out);
    }
}

// Round 14
// 307.437 us; speedup vs baseline: 1.0516x; 1.0152x over previous
//
#include <hip/hip_runtime.h>
#include <cstdint>
#include <cstddef>

#define TAU_D 2.053748910631823
#define M_DIM 8192
#define N_DIM 4096
#define K_DIM 4096
#define NIT   32               // iterations; each covers 2 K-steps of BK=64

typedef float f32x4  __attribute__((ext_vector_type(4)));
typedef short bf16x8 __attribute__((ext_vector_type(8)));

typedef __attribute__((address_space(1))) void gvoid_t;
typedef __attribute__((address_space(3))) void lvoid_t;

__device__ __forceinline__ void gload_lds16(const void* g, void* l) {
    __builtin_amdgcn_global_load_lds((const gvoid_t*)g, (lvoid_t*)l, 16, 0, 0);
}

__device__ __forceinline__ unsigned int pack2bf(float lo, float hi) {
    unsigned int ul = __float_as_uint(lo);
    unsigned int uh = __float_as_uint(hi);
    ul = (ul + 0x7FFFu + ((ul >> 16) & 1u)) >> 16;
    uh = (uh + 0x7FFFu + ((uh >> 16) & 1u)) >> 16;
    return ul | (uh << 16);
}

// fp32 -> bf16 (RNE), vectorized: 16B in / 8B out per thread per iter.
__global__ void cvt_f32_to_bf16(const float4* __restrict__ in,
                                uint2* __restrict__ out, int n4) {
    int i = blockIdx.x * blockDim.x + threadIdx.x;
    const int stride = gridDim.x * blockDim.x;
    for (; i < n4; i += stride) {
        float4 a = in[i];
        uint2 o;
        o.x = pack2bf(a.x, a.y);
        o.y = pack2bf(a.z, a.w);
        out[i] = o;
    }
}

// Raw barrier + compiler-only memory fence.
#define BAR() do { __builtin_amdgcn_s_barrier(); \
                   asm volatile("" ::: "memory"); } while (0)

// ============================================================================
// Phase = [reads(p); stage(p); (vmcnt); BAR; MFMA(p)] -- reads issue BEFORE
// the barrier (latency hides under barrier wait, m201 property) with ONE
// barrier per phase (8/iter, r13 property).
// WAR safety BY CONSTRUCTION: every region's restage phase is >=2 phases
// after its last read:  R1A read ph7(prev) -> staged ph1-2 ; R0B read ph2 ->
// staged ph4-5 ; R0A read ph3 -> staged ph6-7 ; R1B read ph6 -> staged ph8.
// With one barrier/phase, wave w staging at p passed BAR(p-1), which all
// waves reach only after issuing MFMA(q<=p-2) whose lgkmcnt forced their
// region reads complete -> no read/write race.
// vmcnt BEFORE the barrier (publication): ledger (steady state, issue order
// [B(kb)x4 prev-ph8][A(kb)x4 ph1-2][B(ka+2)h0x2 ph4] at ph4 -> vmcnt(2)
// forces A(kb),B(kb); [B(ka+2)x4][A(ka+2)x4][B(kb+2)x4] at ph8 -> vmcnt(4)
// forces A,B(ka+2). Tail: ph4 vmcnt(0). Prologue: vmcnt(4)+BAR.
// Geometry/swizzle/XCD map/epilogue identical to r6-r13 (absmax 2.0).
// ============================================================================
__global__ __launch_bounds__(512, 2) void gemm_masked8(
    const unsigned short* __restrict__ Ab,   // x bf16 [M][K]
    const unsigned short* __restrict__ Bb,   // W bf16 [N][K]
    const float* __restrict__ X,             // x fp32 (mask)
    const float* __restrict__ Wt,            // W fp32 (mask)
    const float* __restrict__ bias,
    float* __restrict__ out)
{
    __shared__ __align__(16) char lds[131072];   // R0A|R0B|R1A|R1B x 32KB

    const int tid  = threadIdx.x;
    const int wave = tid >> 6;
    const int lane = tid & 63;
    const int lr = lane & 15;
    const int lq = lane >> 4;
    const int wm = wave >> 2;    // 0..1 : row half (128 rows)
    const int wn = wave & 3;     // 0..3 : 64-col slice

    // Concurrency-aware XCD cluster map (verified r6).
    const int flat = blockIdx.x;
    const int xcd  = flat & 7;
    const int s    = flat >> 3;            // 0..63
    const int rnd  = s >> 5;               // 0..1
    const int jj   = s & 31;               // 0..31
    const int trow = rnd * 16 + ((xcd >> 2) << 3) + (jj >> 2);   // 0..31
    const int tcol = ((xcd & 3) << 2) + (jj & 3);                // 0..15
    const int rowBase = trow * 256;
    const int colBase = tcol * 256;

    f32x4 acc[8][4];
    #pragma unroll
    for (int i = 0; i < 8; ++i)
        #pragma unroll
        for (int n = 0; n < 4; ++n)
            acc[i][n] = (f32x4){0.f, 0.f, 0.f, 0.f};

    // ---- staging (r6-verified): linear LDS dest; global col pre-swizzled --
    const int srow  = tid >> 3;                       // 0..63
    const int sslot = (tid & 7) ^ (srow & 7);
    const unsigned short* aSrc =
        Ab + (size_t)(rowBase + srow) * K_DIM + sslot * 8;
    const unsigned short* bSrc =
        Bb + (size_t)(colBase + srow) * K_DIM + sslot * 8;

    const unsigned R0A = 0, R0B = 32768, R1A = 65536, R1B = 98304;

    auto stageHalfA = [&](int kst, unsigned reg, int h) {
        #pragma unroll
        for (int i = 2 * h; i < 2 * h + 2; ++i)
            gload_lds16(aSrc + (size_t)i * 64 * K_DIM + kst * 64,
                        lds + reg + i * 8192 + wave * 1024);
    };
    auto stageHalfB = [&](int kst, unsigned reg, int h) {
        #pragma unroll
        for (int i = 2 * h; i < 2 * h + 2; ++i)
            gload_lds16(bSrc + (size_t)i * 64 * K_DIM + kst * 64,
                        lds + reg + i * 8192 + wave * 1024);
    };

    // ---- ds_read offsets (r6-verified swizzle) ----
    const unsigned kk0 = (unsigned)((lq) ^ (lr & 7)) * 16;
    const unsigned kk1 = (unsigned)((4 + lq) ^ (lr & 7)) * 16;
    const unsigned rowA = (unsigned)(wm * 128 + lr) * 128;   // + m*2048
    const unsigned rowB = (unsigned)(wn * 64 + lr) * 128;    // + nf*2048

    // ---- prologue: A(0),B(0)->R0; B(1)->R1B; vmcnt(4); publication BAR ----
    stageHalfA(0, R0A, 0); stageHalfA(0, R0A, 1);
    stageHalfB(0, R0B, 0); stageHalfB(0, R0B, 1);
    stageHalfB(1, R1B, 0); stageHalfB(1, R1B, 1);
    asm volatile("s_waitcnt vmcnt(4)" ::: "memory");   // A0,B0 landed
    BAR();

    bf16x8 aF[4][2];     // A quadrant (q0 ph1-2 / q1 ph3-4; reloaded per half)
    bf16x8 bF0[2][2];    // B nq0 (lives ph1..ph4 of its K-step)
    bf16x8 bF1[2][2];    // B nq1 (lives ph2..ph3)

    #define MFMA_QUAD(ACC_M, ACC_N, BREG)                                      \
        do {                                                                   \
            __builtin_amdgcn_s_setprio(1);                                     \
            _Pragma("unroll")                                                  \
            for (int m = 0; m < 4; ++m)                                        \
                _Pragma("unroll")                                              \
                for (int n = 0; n < 2; ++n)                                    \
                    _Pragma("unroll")                                          \
                    for (int ks = 0; ks < 2; ++ks)                             \
                        acc[(ACC_M) + m][(ACC_N) + n] =                        \
                            __builtin_amdgcn_mfma_f32_16x16x32_bf16(           \
                                aF[m][ks], BREG[n][ks],                        \
                                acc[(ACC_M) + m][(ACC_N) + n], 0, 0, 0);       \
            __builtin_amdgcn_s_setprio(0);                                     \
        } while (0)

    for (int j = 0; j < NIT; ++j) {
        const int ka = 2 * j;
        const int kb = 2 * j + 1;
        const bool stg = (j + 1 < NIT);

        // ---- ph1: reads A q0 + B nq0 (R0); stage A(kb)h0->R1A; BAR; MFMA --
        #pragma unroll
        for (int m = 0; m < 4; ++m) {
            aF[m][0] = *(const bf16x8*)(lds + R0A + rowA + m * 2048 + kk0);
            aF[m][1] = *(const bf16x8*)(lds + R0A + rowA + m * 2048 + kk1);
        }
        #pragma unroll
        for (int n = 0; n < 2; ++n) {
            bF0[n][0] = *(const bf16x8*)(lds + R0B + rowB + n * 2048 + kk0);
            bF0[n][1] = *(const bf16x8*)(lds + R0B + rowB + n * 2048 + kk1);
        }
        stageHalfA(kb, R1A, 0);
        BAR();
        MFMA_QUAD(0, 0, bF0);

        // ---- ph2: reads B nq1 (R0); stage A(kb)h1->R1A; BAR; MFMA ----
        #pragma unroll
        for (int n = 0; n < 2; ++n) {
            bF1[n][0] = *(const bf16x8*)(lds + R0B + rowB + (2 + n) * 2048 + kk0);
            bF1[n][1] = *(const bf16x8*)(lds + R0B + rowB + (2 + n) * 2048 + kk1);
        }
        stageHalfA(kb, R1A, 1);
        BAR();
        MFMA_QUAD(0, 2, bF1);

        // ---- ph3: reads A q1 (R0); BAR; MFMA ----
        #pragma unroll
        for (int m = 0; m < 4; ++m) {
            aF[m][0] = *(const bf16x8*)(lds + R0A + rowA + (4 + m) * 2048 + kk0);
            aF[m][1] = *(const bf16x8*)(lds + R0A + rowA + (4 + m) * 2048 + kk1);
        }
        BAR();
        MFMA_QUAD(4, 2, bF1);

        // ---- ph4: stage B(ka+2)h0->R0B; vmcnt; BAR; MFMA ----
        if (stg) {
            stageHalfB(ka + 2, R0B, 0);
            asm volatile("s_waitcnt vmcnt(2)" ::: "memory");  // A(kb),B(kb) landed
        } else {
            asm volatile("s_waitcnt vmcnt(0)" ::: "memory");  // tail drain
        }
        BAR();
        MFMA_QUAD(4, 0, bF0);

        // ---- ph5: reads A q0 + B nq0 (R1); stage B(ka+2)h1->R0B; BAR; MFMA
        #pragma unroll
        for (int m = 0; m < 4; ++m) {
            aF[m][0] = *(const bf16x8*)(lds + R1A + rowA + m * 2048 + kk0);
            aF[m][1] = *(const bf16x8*)(lds + R1A + rowA + m * 2048 + kk1);
        }
        #pragma unroll
        for (int n = 0; n < 2; ++n) {
            bF0[n][0] = *(const bf16x8*)(lds + R1B + rowB + n * 2048 + kk0);
            bF0[n][1] = *(const bf16x8*)(lds + R1B + rowB + n * 2048 + kk1);
        }
        if (stg) stageHalfB(ka + 2, R0B, 1);
        BAR();
        MFMA_QUAD(0, 0, bF0);

        // ---- ph6: reads B nq1 (R1); stage A(ka+2)h0->R0A; BAR; MFMA ----
        #pragma unroll
        for (int n = 0; n < 2; ++n) {
            bF1[n][0] = *(const bf16x8*)(lds + R1B + rowB + (2 + n) * 2048 + kk0);
            bF1[n][1] = *(const bf16x8*)(lds + R1B + rowB + (2 + n) * 2048 + kk1);
        }
        if (stg) stageHalfA(ka + 2, R0A, 0);
        BAR();
        MFMA_QUAD(0, 2, bF1);

        // ---- ph7: reads A q1 (R1); stage A(ka+2)h1->R0A; BAR; MFMA ----
        #pragma unroll
        for (int m = 0; m < 4; ++m) {
            aF[m][0] = *(const bf16x8*)(lds + R1A + rowA + (4 + m) * 2048 + kk0);
            aF[m][1] = *(const bf16x8*)(lds + R1A + rowA + (4 + m) * 2048 + kk1);
        }
        if (stg) stageHalfA(ka + 2, R0A, 1);
        BAR();
        MFMA_QUAD(4, 2, bF1);

        // ---- ph8: stage B(kb+2)x4->R1B; vmcnt(4); BAR; MFMA ----
        if (stg) {
            stageHalfB(kb + 2, R1B, 0);
            stageHalfB(kb + 2, R1B, 1);
            asm volatile("s_waitcnt vmcnt(4)" ::: "memory");  // A,B(ka+2) landed
        }
        BAR();
        MFMA_QUAD(4, 0, bF0);
    }

    // ---- epilogue: bit-exact fp32 mask + bias + store (verified r3-r13) ---
    __syncthreads();
    float* x0s = (float*)(lds);            // [256][16] f32, 16KB
    float* w0s = (float*)(lds + 16384);    // [256][16] f32
    #pragma unroll
    for (int i = 0; i < 2; ++i) {
        int idx = tid + i * 512;           // 1024 float4 slots
        int r = idx >> 2, qq = (idx & 3) << 2;
        *(f32x4*)(x0s + r * 16 + qq) =
            *(const f32x4*)(X + (size_t)(rowBase + r) * K_DIM + qq);
        *(f32x4*)(w0s + r * 16 + qq) =
            *(const f32x4*)(Wt + (size_t)(colBase + r) * K_DIM + qq);
    }
    __syncthreads();

    const float TAU32 = (float)TAU_D;

    // n in adjacent pairs: both 64B halves of each 128B output line stored
    // back-to-back (write-amplification fix, verified r6-r13).
    #pragma unroll
    for (int np = 0; np < 4; np += 2) {
        float wv[2][16];
        float bv[2];
        #pragma unroll
        for (int e = 0; e < 2; ++e) {
            const int c = wn * 64 + (np + e) * 16 + lr;
            #pragma unroll
            for (int q = 0; q < 4; ++q)
                *(f32x4*)&wv[e][q * 4] = *(const f32x4*)(w0s + c * 16 + q * 4);
            bv[e] = bias[colBase + c];
        }
        #pragma unroll
        for (int mi = 0; mi < 8; ++mi) {
            #pragma unroll
            for (int jr = 0; jr < 4; ++jr) {
                const int rw = wm * 128 + mi * 16 + lq * 4 + jr;
                float xv[16];
                #pragma unroll
                for (int q = 0; q < 4; ++q)
                    *(f32x4*)&xv[q * 4] = *(const f32x4*)(x0s + rw * 16 + q * 4);
                const size_t orow = (size_t)(rowBase + rw) * N_DIM + colBase;
                #pragma unroll
                for (int e = 0; e < 2; ++e) {
                    const int n = np + e;
                    // Replicate BLAS sgemm: single-acc fma chain, k ascending.
                    float y1 = 0.f, s2 = 0.f;
                    #pragma unroll
                    for (int k = 0; k < 16; ++k) {
                        float xk = xv[k], wk = wv[e][k];
                        float xx = xk * xk, ww = wk * wk;
                        y1 = fmaf(xk, wk, y1);
                        s2 = fmaf(xx, ww, s2);
                    }
                    float t = fabsf(y1) / sqrtf(s2 * 0.0625f);
                    float v = (t < TAU32) ? 0.0f : (acc[mi][n][jr] + bv[e]);
                    out[orow + wn * 64 + n * 16 + lr] = v;
                }
            }
        }
    }
}

// ============================================================================
// Fallback (no workspace): round-3 verified 128x128 kernel, reg-staged cvt.
// ============================================================================
__global__ __launch_bounds__(256, 2) void gemm_masked_fb(
    const float* __restrict__ X, const float* __restrict__ Wt,
    const float* __restrict__ bias, float* __restrict__ out)
{
    __shared__ __align__(16) unsigned short As[128 * 32];
    __shared__ __align__(16) unsigned short Bs[128 * 32];

    const int tid  = threadIdx.x;
    const int wave = tid >> 6;
    const int lane = tid & 63;
    const int rowBase = blockIdx.y * 128;
    const int colBase = blockIdx.x * 128;
    const int wr = wave >> 1;
    const int wc = wave & 1;
    const int lr = lane & 15;
    const int lq = lane >> 4;

    f32x4 acc[4][4];
    #pragma unroll
    for (int m = 0; m < 4; ++m)
        #pragma unroll
        for (int n = 0; n < 4; ++n)
            acc[m][n] = (f32x4){0.f, 0.f, 0.f, 0.f};

    const int srow = tid >> 2;
    const int scol = (tid & 3) * 8;
    const float* afp = X  + (size_t)(rowBase + srow) * K_DIM + scol;
    const float* bfp = Wt + (size_t)(colBase + srow) * K_DIM + scol;

    for (int kt = 0; kt < K_DIM; kt += 32) {
        #pragma unroll
        for (int issue = 0; issue < 2; ++issue) {
            const float* sa = afp + (size_t)issue * 64 * K_DIM;
            const float* sb = bfp + (size_t)issue * 64 * K_DIM;
            float4 a0 = *(const float4*)(sa);
            float4 a1 = *(const float4*)(sa + 4);
            float4 b0 = *(const float4*)(sb);
            float4 b1 = *(const float4*)(sb + 4);
            uint4 pa, pb;
            pa.x = pack2bf(a0.x, a0.y); pa.y = pack2bf(a0.z, a0.w);
            pa.z = pack2bf(a1.x, a1.y); pa.w = pack2bf(a1.z, a1.w);
            pb.x = pack2bf(b0.x, b0.y); pb.y = pack2bf(b0.z, b0.w);
            pb.z = pack2bf(b1.x, b1.y); pb.w = pack2bf(b1.z, b1.w);
            *(uint4*)((char*)As + issue * 4096 + tid * 16) = pa;
            *(uint4*)((char*)Bs + issue * 4096 + tid * 16) = pb;
        }
        afp += 32; bfp += 32;
        __syncthreads();

        bf16x8 af[4], bq[4];
        #pragma unroll
        for (int m = 0; m < 4; ++m)
            af[m] = *(const bf16x8*)(As + (wr * 64 + m * 16 + lr) * 32 + lq * 8);
        #pragma unroll
        for (int n = 0; n < 4; ++n)
            bq[n] = *(const bf16x8*)(Bs + (wc * 64 + n * 16 + lr) * 32 + lq * 8);
        #pragma unroll
        for (int m = 0; m < 4; ++m)
            #pragma unroll
            for (int n = 0; n < 4; ++n)
                acc[m][n] = __builtin_amdgcn_mfma_f32_16x16x32_bf16(
                    af[m], bq[n], acc[m][n], 0, 0, 0);
        __syncthreads();
    }

    float* x0s = (float*)As;
    float* w0s = (float*)Bs;
    #pragma unroll
    for (int i = 0; i < 2; ++i) {
        int idx = tid + i * 256;
        int r = idx >> 2, q = (idx & 3) * 4;
        *(float4*)(x0s + r * 16 + q) =
            *(const float4*)(X + (size_t)(rowBase + r) * K_DIM + q);
        *(float4*)(w0s + r * 16 + q) =
            *(const float4*)(Wt + (size_t)(colBase + r) * K_DIM + q);
    }
    __syncthreads();

    const float TAU32 = (float)TAU_D;
    float wv[4][16];
    float bv[4];
    #pragma unroll
    for (int n = 0; n < 4; ++n) {
        int c = wc * 64 + n * 16 + lr;
        #pragma unroll
        for (int q = 0; q < 4; ++q)
            *(f32x4*)&wv[n][q * 4] = *(const f32x4*)(w0s + c * 16 + q * 4);
        bv[n] = bias[colBase + c];
    }

    #pragma unroll
    for (int m = 0; m < 4; ++m) {
        #pragma unroll
        for (int j = 0; j < 4; ++j) {
            const int r = wr * 64 + m * 16 + lq * 4 + j;
            float xv[16];
            #pragma unroll
            for (int q = 0; q < 4; ++q)
                *(f32x4*)&xv[q * 4] = *(const f32x4*)(x0s + r * 16 + q * 4);
            const size_t orow = (size_t)(rowBase + r) * N_DIM + colBase;
            #pragma unroll
            for (int n = 0; n < 4; ++n) {
                float y1 = 0.f, s2 = 0.f;
                #pragma unroll
                for (int k = 0; k < 16; ++k) {
                    float xk = xv[k];
                    float wk = wv[n][k];
                    float xx = xk * xk;
                    float ww = wk * wk;
                    y1 = fmaf(xk, wk, y1);
                    s2 = fmaf(xx, ww, s2);
                }
                float t = fabsf(y1) / sqrtf(s2 * 0.0625f);
                float v = (t < TAU32) ? 0.0f : (acc[m][n][j] + bv[n]);
                out[orow + wc * 64 + n * 16 + lr] = v;
            }
        }
    }
}

extern "C" void kernel_launch(void* const* d_in, const int* in_sizes, int n_in,
                              void* d_out, int out_size, void* d_ws, size_t ws_size,
                              hipStream_t stream) {
    const float* x    = (const float*)d_in[0];
    const float* W    = (const float*)d_in[1];
    const float* bias = (const float*)d_in[2];
    float* out = (float*)d_out;

    const size_t needA = (size_t)M_DIM * K_DIM * 2;   // 64 MB
    const size_t needB = (size_t)N_DIM * K_DIM * 2;   // 32 MB

    if (ws_size >= needA + needB) {
        unsigned short* xb = (unsigned short*)d_ws;
        unsigned short* wb = (unsigned short*)((char*)d_ws + needA);
        cvt_f32_to_bf16<<<2048, 256, 0, stream>>>(
            (const float4*)x, (uint2*)xb, (M_DIM * K_DIM) / 4);
        cvt_f32_to_bf16<<<2048, 256, 0, stream>>>(
            (const float4*)W, (uint2*)wb, (N_DIM * K_DIM) / 4);
        dim3 grid((M_DIM / 256) * (N_DIM / 256));     // 512 blocks, 1-D
        gemm_masked8<<<grid, 512, 0, stream>>>(xb, wb, x, W, bias, out);
    } else {
        dim3 grid(N_DIM / 128, M_DIM / 128);
        gemm_masked_fb<<<grid, 256, 0, stream>>>(x, W, bias, out);
    }
}